// Round 6
// baseline (1610.133 us; speedup 1.0000x reference)
//
#include <hip/hip_runtime.h>

#define E_N 262144
#define T_N 1048576

typedef short  bf16x8  __attribute__((ext_vector_type(8)));
typedef short  bf16x4v __attribute__((ext_vector_type(4)));
typedef float  f32x4   __attribute__((ext_vector_type(4)));

// wreg offsets (ushort units)
#define OFF_KJ    0
#define OFF_DOWN  16384
#define OFF_UP    24576
#define OFF_JI    32768
#define OFF_GU    49152
#define OFF_CN    65536
#define OFF_RB0   81920
#define OFF_RB1   98304
#define OFF_LIN   114688
#define OFF_RA00  131072
#define OFF_RA01  147456
#define OFF_RA10  163840
#define OFF_RA11  180224
#define OFF_END   196608   // W12 (f32[6][128]) follows
#define WREG_BYTES 524288u

// byte offsets inside the e2 slot (fallback layout)
#define OFFB_AGG   0u
#define OFFB_XKJ   33554432u
#define OFFB_WREG  67108864u
#define OFFB_CNT   67633152u
#define OFFB_POS   68683776u
#define OFFB_TRI   69732352u
#define OFFB_BS    73926656u
#define OFFB_BP    73927680u

__device__ __forceinline__ float silu_f(float x) { return x / (1.0f + __expf(-x)); }

__device__ __forceinline__ unsigned short f2bf(float f) {
  union { float f; unsigned int u; } v; v.f = f;
  unsigned int u = v.u;
  return (unsigned short)((u + 0x7fffu + ((u >> 16) & 1u)) >> 16);   // RNE
}
__device__ __forceinline__ float bf2f(unsigned short h) {
  union { unsigned int u; float f; } v; v.u = ((unsigned int)h) << 16;
  return v.f;
}

__device__ __forceinline__ unsigned cvtpk(float lo, float hi) {
  unsigned r;
  asm("v_cvt_pk_bf16_f32 %0, %1, %2" : "=v"(r) : "v"(lo), "v"(hi));
  return r;
}

// ---- stage [NR][NC] f32 global tile -> swizzled bf16 LDS tile ----
template<int NC, int NR, int NTH>
__device__ __forceinline__ void stage_tile(const float* __restrict__ g, char* __restrict__ lds) {
  constexpr int RB = NC * 2;
  constexpr int C4 = NC / 4;
  for (int i = threadIdx.x; i < NR * C4; i += NTH) {
    int r = i / C4, c4 = i % C4;
    float4 v = *(const float4*)(g + (size_t)r * NC + c4 * 4);
    bf16x4v h;
    h[0] = (short)f2bf(v.x); h[1] = (short)f2bf(v.y);
    h[2] = (short)f2bf(v.z); h[3] = (short)f2bf(v.w);
    *(bf16x4v*)(lds + r * RB + ((c4 * 8) ^ ((r & 7) << 4))) = h;
  }
}

// ---- stage [128][64] bf16 global tile -> swizzled LDS (straight copy), 1024 thr ----
__device__ __forceinline__ void stage_tile_bf16_128x64(const unsigned short* __restrict__ g,
                                                       char* __restrict__ lds) {
  int i = threadIdx.x;            // 1024 threads, 1024 16B-chunks (128 rows x 8)
  int r = i >> 3, c = i & 7;
  int4 v = *(const int4*)((const char*)g + r * 128 + c * 16);
  *(int4*)(lds + r * 128 + ((c * 16) ^ ((r & 7) << 4))) = v;
}

// ---- MFMA GEMM: swizzled LDS A-tile  @  WT[N][K] bf16 (global) ----
template<int MREP, int NREP, int KSTEPS, int RB>
__device__ __forceinline__ void mfma_gemm(const char* __restrict__ lds, int row0, int col0,
                                          const unsigned short* __restrict__ WT, int lane,
                                          f32x4 (&acc)[MREP][NREP]) {
  const int kg = lane >> 4, r15 = lane & 15;
#pragma unroll
  for (int m = 0; m < MREP; ++m)
#pragma unroll
    for (int n = 0; n < NREP; ++n) acc[m][n] = (f32x4){0.f, 0.f, 0.f, 0.f};
#pragma unroll
  for (int kk = 0; kk < KSTEPS; ++kk) {
    bf16x8 a[MREP], bfr[NREP];
#pragma unroll
    for (int m = 0; m < MREP; ++m) {
      int row = row0 + m * 16 + r15;
      a[m] = *(const bf16x8*)(lds + row * RB + ((kk * 64 + kg * 16) ^ ((row & 7) << 4)));
    }
#pragma unroll
    for (int n = 0; n < NREP; ++n) {
      int nc = col0 + n * 16 + r15;
      bfr[n] = *(const bf16x8*)((const short*)WT + nc * (KSTEPS * 32) + kk * 32 + kg * 8);
    }
#pragma unroll
    for (int m = 0; m < MREP; ++m)
#pragma unroll
      for (int n = 0; n < NREP; ++n)
        acc[m][n] = __builtin_amdgcn_mfma_f32_16x16x32_bf16(a[m], bfr[n], acc[m][n], 0, 0, 0);
  }
}

// ---- write 2x2 fragment set (f32) as bf16 into swizzled LDS tile (cvt_pk packed) ----
template<int RB>
__device__ __forceinline__ void write_cd(char* __restrict__ lds, int wrow, int wcol, int lane,
                                         const f32x4 (&v)[2][2]) {
  const int kg = lane >> 4, r15 = lane & 15;
#pragma unroll
  for (int m = 0; m < 2; ++m)
#pragma unroll
    for (int n = 0; n < 2; ++n) {
      int col2 = (wcol + n * 16 + r15) * 2;
      int row0 = wrow + m * 16 + kg * 4;
      unsigned u0 = cvtpk(v[m][n][0], v[m][n][1]);
      unsigned u1 = cvtpk(v[m][n][2], v[m][n][3]);
      *(unsigned short*)(lds + (row0 + 0) * RB + (col2 ^ (((row0 + 0) & 7) << 4))) = (unsigned short)u0;
      *(unsigned short*)(lds + (row0 + 1) * RB + (col2 ^ (((row0 + 1) & 7) << 4))) = (unsigned short)(u0 >> 16);
      *(unsigned short*)(lds + (row0 + 2) * RB + (col2 ^ (((row0 + 2) & 7) << 4))) = (unsigned short)u1;
      *(unsigned short*)(lds + (row0 + 3) * RB + (col2 ^ (((row0 + 3) & 7) << 4))) = (unsigned short)(u1 >> 16);
    }
}

// ---- prep: transpose weights to bf16 WT[N][K]; W12 = W_rbf1@W_rbf2 ----
__global__ void __launch_bounds__(256) k_prep(
    const float* __restrict__ W_kj, const float* __restrict__ W_down,
    const float* __restrict__ W_up, const float* __restrict__ W_ji,
    const float* __restrict__ W_get_up, const float* __restrict__ W_connect,
    const float* __restrict__ rbW, const float* __restrict__ W_lin,
    const float* __restrict__ raW,
    const float* __restrict__ W_rbf1, const float* __restrict__ W_rbf2,
    unsigned short* __restrict__ wreg) {
  int b = blockIdx.x;
  if (b == 13) {
    float* W12 = (float*)(wreg + OFF_END);
    for (int i = threadIdx.x; i < 768; i += 256) {
      int r = i >> 7, n = i & 127;
      float s = 0.f;
#pragma unroll
      for (int q = 0; q < 8; ++q) s += W_rbf1[r * 8 + q] * W_rbf2[q * 128 + n];
      W12[i] = s;
    }
    return;
  }
  const float* src; int K = 128, N = 128; int off;
  switch (b) {
    case 0:  src = W_kj;          off = OFF_KJ;  break;
    case 1:  src = W_down;        off = OFF_DOWN; N = 64;  break;
    case 2:  src = W_up;          off = OFF_UP;   K = 64;  break;
    case 3:  src = W_ji;          off = OFF_JI;  break;
    case 4:  src = W_get_up;      off = OFF_GU;  break;
    case 5:  src = W_connect;     off = OFF_CN;  break;
    case 6:  src = rbW;           off = OFF_RB0; break;
    case 7:  src = rbW + 16384;   off = OFF_RB1; break;
    case 8:  src = W_lin;         off = OFF_LIN; break;
    case 9:  src = raW;           off = OFF_RA00; break;
    case 10: src = raW + 16384;   off = OFF_RA01; break;
    case 11: src = raW + 32768;   off = OFF_RA10; break;
    default: src = raW + 49152;   off = OFF_RA11; break;
  }
  unsigned short* dst = wreg + off;
  for (int i = threadIdx.x; i < K * N; i += 256) {
    int k = i / N, n = i % N;
    dst[n * K + k] = f2bf(src[i]);
  }
}

// ================= CSR build (by idx_ji) =================
__global__ void __launch_bounds__(256) k_hist(const int* __restrict__ idx_ji,
                                              int* __restrict__ counts) {
  int t = blockIdx.x * 256 + threadIdx.x;
  atomicAdd(&counts[idx_ji[t]], 1);
}

__global__ void __launch_bounds__(1024) k_scan1(const int* __restrict__ counts,
                                                int* __restrict__ locpre,
                                                int* __restrict__ bsum) {
  __shared__ int s[1024];
  int i = blockIdx.x * 1024 + threadIdx.x;
  int v = counts[i];
  s[threadIdx.x] = v; __syncthreads();
  for (int o = 1; o < 1024; o <<= 1) {
    int t = (threadIdx.x >= o) ? s[threadIdx.x - o] : 0;
    __syncthreads();
    s[threadIdx.x] += t;
    __syncthreads();
  }
  locpre[i] = s[threadIdx.x] - v;
  if (threadIdx.x == 1023) bsum[blockIdx.x] = s[1023];
}

__global__ void __launch_bounds__(256) k_scan2(const int* __restrict__ bsum,
                                               int* __restrict__ bpre, int* __restrict__ offs) {
  __shared__ int s[256];
  int v = bsum[threadIdx.x];
  s[threadIdx.x] = v; __syncthreads();
  for (int o = 1; o < 256; o <<= 1) {
    int t = (threadIdx.x >= o) ? s[threadIdx.x - o] : 0;
    __syncthreads();
    s[threadIdx.x] += t;
    __syncthreads();
  }
  bpre[threadIdx.x] = s[threadIdx.x] - v;
  if (threadIdx.x == 0) offs[E_N] = T_N;
}

__global__ void __launch_bounds__(1024) k_scan3(const int* __restrict__ locpre,
                                                const int* __restrict__ bpre,
                                                int* __restrict__ offs,
                                                int* __restrict__ pos) {
  int i = blockIdx.x * 1024 + threadIdx.x;
  int v = locpre[i] + bpre[blockIdx.x];
  offs[i] = v;
  pos[i] = v;
}

__global__ void __launch_bounds__(256) k_fill(const int* __restrict__ idx_ji,
                                              int* __restrict__ pos, int* __restrict__ tri) {
  int t = blockIdx.x * 256 + threadIdx.x;
  int e = idx_ji[t];
  int slot = atomicAdd(&pos[e], 1);
  tri[slot] = t;
}

// ================= dense sbf_p: [T][64] bf16 =================
__global__ void __launch_bounds__(256) k_sbfp(const float* __restrict__ sbf,
                                              const float* __restrict__ W_sbf1,
                                              const float* __restrict__ W_sbf2,
                                              unsigned int* __restrict__ sbfp) {
  __shared__ float s_s[8][42];
  __shared__ float s_t8[8][8];
  int t0 = blockIdx.x * 8;
  for (int i = threadIdx.x; i < 8 * 42; i += 256)
    s_s[i / 42][i % 42] = sbf[(size_t)t0 * 42 + i];
  __syncthreads();
  if (threadIdx.x < 64) {
    int w8 = threadIdx.x >> 3, bb = threadIdx.x & 7;
    float s = 0.f;
#pragma unroll
    for (int r = 0; r < 42; ++r) s += s_s[w8][r] * W_sbf1[r * 8 + bb];
    s_t8[w8][bb] = s;
  }
  __syncthreads();
  int w8 = threadIdx.x >> 5, jj = threadIdx.x & 31;
  float sp0 = 0.f, sp1 = 0.f;
#pragma unroll
  for (int bb = 0; bb < 8; ++bb) {
    float tv = s_t8[w8][bb];
    sp0 += tv * W_sbf2[bb * 64 + jj * 2];
    sp1 += tv * W_sbf2[bb * 64 + jj * 2 + 1];
  }
  unsigned int u = (unsigned int)f2bf(sp0) | ((unsigned int)f2bf(sp1) << 16);
  sbfp[(size_t)(t0 + w8) * 32 + jj] = u;
}

// ================= gather: agg[e][j] = sum_t sbfp[t][j]*xkj[idx_kj[t]][j] =================
__global__ void __launch_bounds__(256) k_aggB(const int* __restrict__ offs,
                                              const int* __restrict__ tri,
                                              const int* __restrict__ idx_kj,
                                              const unsigned int* __restrict__ sbfp,
                                              const unsigned int* __restrict__ xkj,
                                              unsigned int* __restrict__ agg) {
  int sub = threadIdx.x >> 5, jj = threadIdx.x & 31;
  int e = blockIdx.x * 8 + sub;
  int o0 = offs[e], o1 = offs[e + 1];
  float a0 = 0.f, a1 = 0.f;
  for (int i = o0; i < o1; ++i) {
    int t = tri[i];
    int kj = idx_kj[t];
    unsigned int sv = sbfp[(size_t)t * 32 + jj];
    unsigned int xv = xkj[(size_t)kj * 32 + jj];
    a0 += bf2f((unsigned short)(sv & 0xffff)) * bf2f((unsigned short)(xv & 0xffff));
    a1 += bf2f((unsigned short)(sv >> 16)) * bf2f((unsigned short)(xv >> 16));
  }
  agg[(size_t)e * 32 + jj] = (unsigned int)f2bf(a0) | ((unsigned int)f2bf(a1) << 16);
}

// ================= gather: x_up_raw[e][h] = sum_t x1[t][h] =================
__global__ void __launch_bounds__(256) k_xupg(const int* __restrict__ offs,
                                              const int* __restrict__ tri,
                                              const float* __restrict__ x1,
                                              float* __restrict__ out) {
  int sub = threadIdx.x >> 6, h2 = threadIdx.x & 63;
  int e = blockIdx.x * 4 + sub;
  int o0 = offs[e], o1 = offs[e + 1];
  float a0 = 0.f, a1 = 0.f;
  for (int i = o0; i < o1; ++i) {
    int t = tri[i];
    float2 v = *(const float2*)(x1 + (size_t)t * 128 + h2 * 2);
    a0 += v.x; a1 += v.y;
  }
  *(float2*)(out + (size_t)e * 128 + h2 * 2) = make_float2(a0, a1);
}

// ================= Phase A: 128-edge tile, 1024 threads =================
__global__ void __launch_bounds__(1024, 8) phaseA(
    const float* __restrict__ x_old, const float* __restrict__ rbf0,
    const unsigned short* __restrict__ wreg,
    const float* __restrict__ b_kj, const float* __restrict__ b_down,
    unsigned short* __restrict__ xkjdown) {
  __shared__ char lds[65536];
  char* B0 = lds;
  char* B1 = lds + 32768;
  const int tid = threadIdx.x, lane = tid & 63, wave = tid >> 6;
  const int kg = lane >> 4, r15 = lane & 15;
  const int wrow = (wave >> 2) * 32, wcol = (wave & 3) * 32;   // 4x4 waves -> 128x128
  const size_t e_base = (size_t)blockIdx.x * 128;
  const float* W12 = (const float*)(wreg + OFF_END);

  stage_tile<128, 128, 1024>(x_old + e_base * 128, B0);
  __syncthreads();

  f32x4 acc[2][2], val[2][2];
  mfma_gemm<2, 2, 4, 256>(B0, wrow, wcol, wreg + OFF_KJ, lane, acc);
#pragma unroll
  for (int n = 0; n < 2; ++n) {
    int col = wcol + n * 16 + r15;
    float bk = b_kj[col];
    float wc[6];
#pragma unroll
    for (int q = 0; q < 6; ++q) wc[q] = W12[q * 128 + col];
#pragma unroll
    for (int m = 0; m < 2; ++m)
#pragma unroll
      for (int r = 0; r < 4; ++r) {
        int row = wrow + m * 16 + kg * 4 + r;
        const float* rp = rbf0 + (e_base + row) * 6;
        float rv = rp[0]*wc[0] + rp[1]*wc[1] + rp[2]*wc[2] + rp[3]*wc[3] + rp[4]*wc[4] + rp[5]*wc[5];
        val[m][n][r] = silu_f(acc[m][n][r] + bk) * rv;
      }
  }
  __syncthreads();
  write_cd<256>(B1, wrow, wcol, lane, val);
  __syncthreads();

  // N=64 GEMM: 16 waves as 8(M) x 2(N): each wave 16 rows x 32 cols
  const int wrow2 = (wave >> 1) * 16, wcol2 = (wave & 1) * 32;
  f32x4 a2[1][2];
  mfma_gemm<1, 2, 4, 256>(B1, wrow2, wcol2, wreg + OFF_DOWN, lane, a2);
#pragma unroll
  for (int n = 0; n < 2; ++n) {
    int col = wcol2 + n * 16 + r15;
    float bd = b_down[col];
#pragma unroll
    for (int r = 0; r < 4; ++r) {
      int row = wrow2 + kg * 4 + r;
      xkjdown[(e_base + row) * 64 + col] = f2bf(silu_f(a2[0][n][r] + bd));
    }
  }
}

// ================= Phase C1: 128-edge tile GEMM chain, writes e1 (+fused e2) =================
__global__ void __launch_bounds__(1024, 8) phaseC1(
    const float* __restrict__ x_old, float* __restrict__ e1buf,
    const unsigned short* __restrict__ agg, const unsigned short* __restrict__ wreg,
    const float* __restrict__ b_up, const float* __restrict__ b_ji,
    const float* __restrict__ b_get_up, const float* __restrict__ b_connect,
    const float* __restrict__ rbB, const float* __restrict__ b_lin,
    const float* __restrict__ raB,
    const float* __restrict__ rbf0, const float* __restrict__ W_rbf,
    float* __restrict__ e2o) {
  __shared__ char lds[65536];
  char* B0 = lds;
  char* B1 = lds + 32768;
  const int tid = threadIdx.x, lane = tid & 63, wave = tid >> 6;
  const int kg = lane >> 4, r15 = lane & 15;
  const int wrow = (wave >> 2) * 32, wcol = (wave & 3) * 32;   // 4x4 waves -> 128x128
  const size_t e_base = (size_t)blockIdx.x * 128;

  stage_tile_bf16_128x64(agg + e_base * 64, B0);      // [128][64] bf16, RB=128
  stage_tile<128, 128, 1024>(x_old + e_base * 128, B1);
  __syncthreads();

  f32x4 acc[2][2], acc2[2][2], keep[2][2], tmp[2][2];

  // S1+S2: e1a = silu(x_old@W_ji+b_ji) + silu(agg@W_up+b_up)
  mfma_gemm<2, 2, 2, 128>(B0, wrow, wcol, wreg + OFF_UP, lane, acc);
  mfma_gemm<2, 2, 4, 256>(B1, wrow, wcol, wreg + OFF_JI, lane, acc2);
#pragma unroll
  for (int n = 0; n < 2; ++n) {
    int col = wcol + n * 16 + r15;
    float bu = b_up[col], bj = b_ji[col];
#pragma unroll
    for (int m = 0; m < 2; ++m)
#pragma unroll
      for (int r = 0; r < 4; ++r)
        keep[m][n][r] = silu_f(acc2[m][n][r] + bj) + silu_f(acc[m][n][r] + bu);
  }
  __syncthreads();
  write_cd<256>(B0, wrow, wcol, lane, keep);
  stage_tile<128, 128, 1024>(e1buf + e_base * 128, B1);    // x_up_raw
  __syncthreads();

  // S3+S4: e1b = silu(e1a@W_connect+b) + silu(x_up_raw@W_get_up+b)
  mfma_gemm<2, 2, 4, 256>(B1, wrow, wcol, wreg + OFF_GU, lane, acc);
  mfma_gemm<2, 2, 4, 256>(B0, wrow, wcol, wreg + OFF_CN, lane, acc2);
#pragma unroll
  for (int n = 0; n < 2; ++n) {
    int col = wcol + n * 16 + r15;
    float bg = b_get_up[col], bc = b_connect[col];
#pragma unroll
    for (int m = 0; m < 2; ++m)
#pragma unroll
      for (int r = 0; r < 4; ++r)
        keep[m][n][r] = silu_f(acc2[m][n][r] + bc) + silu_f(acc[m][n][r] + bg);
  }
  __syncthreads();
  write_cd<256>(B1, wrow, wcol, lane, keep);
  __syncthreads();

  // S5: h = silu(e1b@rb0 + b) -> B0
  mfma_gemm<2, 2, 4, 256>(B1, wrow, wcol, wreg + OFF_RB0, lane, acc);
#pragma unroll
  for (int n = 0; n < 2; ++n) {
    float b0v = rbB[wcol + n * 16 + r15];
#pragma unroll
    for (int m = 0; m < 2; ++m)
#pragma unroll
      for (int r = 0; r < 4; ++r) tmp[m][n][r] = silu_f(acc[m][n][r] + b0v);
  }
  __syncthreads();
  write_cd<256>(B0, wrow, wcol, lane, tmp);
  __syncthreads();

  // S6: e1c = e1b + silu(h@rb1 + b) -> B1
  mfma_gemm<2, 2, 4, 256>(B0, wrow, wcol, wreg + OFF_RB1, lane, acc);
#pragma unroll
  for (int n = 0; n < 2; ++n) {
    float b1v = rbB[128 + wcol + n * 16 + r15];
#pragma unroll
    for (int m = 0; m < 2; ++m)
#pragma unroll
      for (int r = 0; r < 4; ++r) keep[m][n][r] += silu_f(acc[m][n][r] + b1v);
  }
  __syncthreads();
  write_cd<256>(B1, wrow, wcol, lane, keep);
  __syncthreads();

  // S7: e1d = silu(e1c@W_lin + b) + x_old -> B0
  mfma_gemm<2, 2, 4, 256>(B1, wrow, wcol, wreg + OFF_LIN, lane, acc);
#pragma unroll
  for (int n = 0; n < 2; ++n) {
    int col = wcol + n * 16 + r15;
    float bl = b_lin[col];
#pragma unroll
    for (int m = 0; m < 2; ++m)
#pragma unroll
      for (int r = 0; r < 4; ++r) {
        int row = wrow + m * 16 + kg * 4 + r;
        keep[m][n][r] = silu_f(acc[m][n][r] + bl) + x_old[(e_base + row) * 128 + col];
      }
  }
  __syncthreads();
  write_cd<256>(B0, wrow, wcol, lane, keep);
  __syncthreads();

  // S8: h = silu(e1d@ra00 + b) -> B1
  mfma_gemm<2, 2, 4, 256>(B0, wrow, wcol, wreg + OFF_RA00, lane, acc);
#pragma unroll
  for (int n = 0; n < 2; ++n) {
    float bv = raB[wcol + n * 16 + r15];
#pragma unroll
    for (int m = 0; m < 2; ++m)
#pragma unroll
      for (int r = 0; r < 4; ++r) tmp[m][n][r] = silu_f(acc[m][n][r] + bv);
  }
  __syncthreads();
  write_cd<256>(B1, wrow, wcol, lane, tmp);
  __syncthreads();

  // S9: e1e = e1d + silu(h@ra01 + b) -> B0
  mfma_gemm<2, 2, 4, 256>(B1, wrow, wcol, wreg + OFF_RA01, lane, acc);
#pragma unroll
  for (int n = 0; n < 2; ++n) {
    float bv = raB[128 + wcol + n * 16 + r15];
#pragma unroll
    for (int m = 0; m < 2; ++m)
#pragma unroll
      for (int r = 0; r < 4; ++r) keep[m][n][r] += silu_f(acc[m][n][r] + bv);
  }
  __syncthreads();
  write_cd<256>(B0, wrow, wcol, lane, keep);
  __syncthreads();

  // S10: h = silu(e1e@ra10 + b) -> B1
  mfma_gemm<2, 2, 4, 256>(B0, wrow, wcol, wreg + OFF_RA10, lane, acc);
#pragma unroll
  for (int n = 0; n < 2; ++n) {
    float bv = raB[256 + wcol + n * 16 + r15];
#pragma unroll
    for (int m = 0; m < 2; ++m)
#pragma unroll
      for (int r = 0; r < 4; ++r) tmp[m][n][r] = silu_f(acc[m][n][r] + bv);
  }
  __syncthreads();
  write_cd<256>(B1, wrow, wcol, lane, tmp);
  __syncthreads();

  // S11: e1 = e1e + silu(h@ra11 + b) ; optional fused e2
  mfma_gemm<2, 2, 4, 256>(B1, wrow, wcol, wreg + OFF_RA11, lane, acc);
#pragma unroll
  for (int n = 0; n < 2; ++n) {
    int col = wcol + n * 16 + r15;
    float bv = raB[384 + col];
    float wc[6];
#pragma unroll
    for (int q = 0; q < 6; ++q) wc[q] = W_rbf[q * 128 + col];
#pragma unroll
    for (int m = 0; m < 2; ++m)
#pragma unroll
      for (int r = 0; r < 4; ++r) {
        int row = wrow + m * 16 + kg * 4 + r;
        size_t e = e_base + row;
        float val = keep[m][n][r] + silu_f(acc[m][n][r] + bv);
        e1buf[e * 128 + col] = val;
        if (e2o) {
          const float* rp = rbf0 + e * 6;
          float rv = rp[0]*wc[0] + rp[1]*wc[1] + rp[2]*wc[2] + rp[3]*wc[3] + rp[4]*wc[4] + rp[5]*wc[5];
          e2o[e * 128 + col] = val * rv;
        }
      }
  }
}

// ---- fallback C2 epilogue: e2 = (rbf0 @ W_rbf) * e1 ----
__global__ void __launch_bounds__(256) k_e2(const float* __restrict__ e1,
                                            const float* __restrict__ rbf0,
                                            const float* __restrict__ W_rbf,
                                            float* __restrict__ e2) {
  size_t gid = (size_t)blockIdx.x * 256 + threadIdx.x;
  int e = (int)(gid >> 5);
  int c = (int)(gid & 31) << 2;
  float r6[6];
#pragma unroll
  for (int r = 0; r < 6; ++r) r6[r] = rbf0[(size_t)e * 6 + r];
  float4 v = *(const float4*)(e1 + (size_t)e * 128 + c);
  float4 o;
  float rv;
  rv = 0.f;
#pragma unroll
  for (int r = 0; r < 6; ++r) rv += r6[r] * W_rbf[r * 128 + c + 0];
  o.x = v.x * rv;
  rv = 0.f;
#pragma unroll
  for (int r = 0; r < 6; ++r) rv += r6[r] * W_rbf[r * 128 + c + 1];
  o.y = v.y * rv;
  rv = 0.f;
#pragma unroll
  for (int r = 0; r < 6; ++r) rv += r6[r] * W_rbf[r * 128 + c + 2];
  o.z = v.z * rv;
  rv = 0.f;
#pragma unroll
  for (int r = 0; r < 6; ++r) rv += r6[r] * W_rbf[r * 128 + c + 3];
  o.w = v.w * rv;
  *(float4*)(e2 + (size_t)e * 128 + c) = o;
}

extern "C" void kernel_launch(void* const* d_in, const int* in_sizes, int n_in,
                              void* d_out, int out_size, void* d_ws, size_t ws_size,
                              hipStream_t stream) {
  const float* x1        = (const float*)d_in[0];
  const float* x_old     = (const float*)d_in[1];
  const float* rbf0      = (const float*)d_in[2];
  const float* sbf       = (const float*)d_in[3];
  const int*   idx_kj    = (const int*)d_in[4];
  const int*   idx_ji    = (const int*)d_in[5];
  const float* W_rbf1    = (const float*)d_in[6];
  const float* W_rbf2    = (const float*)d_in[7];
  const float* W_sbf1    = (const float*)d_in[8];
  const float* W_sbf2    = (const float*)d_in[9];
  const float* W_rbf     = (const float*)d_in[10];
  const float* W_kj      = (const float*)d_in[11];
  const float* b_kj      = (const float*)d_in[12];
  const float* W_ji      = (const float*)d_in[13];
  const float* b_ji      = (const float*)d_in[14];
  const float* W_connect = (const float*)d_in[15];
  const float* b_connect = (const float*)d_in[16];
  const float* W_get_up  = (const float*)d_in[17];
  const float* b_get_up  = (const float*)d_in[18];
  const float* W_down    = (const float*)d_in[19];
  const float* b_down    = (const float*)d_in[20];
  const float* W_up      = (const float*)d_in[21];
  const float* b_up      = (const float*)d_in[22];
  const float* rbW       = (const float*)d_in[23];
  const float* rbB       = (const float*)d_in[24];
  const float* W_lin     = (const float*)d_in[25];
  const float* b_lin     = (const float*)d_in[26];
  const float* raW       = (const float*)d_in[27];
  const float* raB       = (const float*)d_in[28];

  float* e1buf = (float*)d_out;                      // sbf_p -> x_up_raw -> e1
  char*  base2 = (char*)d_out + (size_t)E_N * 128 * 4;
  float* e2out = (float*)base2;

  unsigned short* xkj_b = (unsigned short*)(base2 + OFFB_XKJ);
  int* counts = (int*)(base2 + OFFB_CNT);
  int* pos    = (int*)(base2 + OFFB_POS);
  int* tri    = (int*)(base2 + OFFB_TRI);
  int* bsum   = (int*)(base2 + OFFB_BS);
  int* bpre   = (int*)(base2 + OFFB_BP);

  const size_t need_ws = (size_t)WREG_BYTES + (size_t)E_N * 64 * 2;
  const bool fuse = ws_size >= need_ws;
  unsigned short* wreg  = fuse ? (unsigned short*)d_ws
                               : (unsigned short*)(base2 + OFFB_WREG);
  unsigned short* agg_b = fuse ? (unsigned short*)((char*)d_ws + WREG_BYTES)
                               : (unsigned short*)(base2 + OFFB_AGG);

  unsigned int* sbfp_u = (unsigned int*)e1buf;   // bf16x2 [T][32] transient in e1 slot

  k_prep<<<14, 256, 0, stream>>>(W_kj, W_down, W_up, W_ji, W_get_up, W_connect,
                                 rbW, W_lin, raW, W_rbf1, W_rbf2, wreg);

  hipMemsetAsync(counts, 0, (E_N + 1) * sizeof(int), stream);
  k_hist<<<T_N / 256, 256, 0, stream>>>(idx_ji, counts);
  k_scan1<<<256, 1024, 0, stream>>>(counts, pos, bsum);
  k_scan2<<<1, 256, 0, stream>>>(bsum, bpre, counts);
  k_scan3<<<256, 1024, 0, stream>>>(pos, bpre, counts, pos);
  k_fill<<<T_N / 256, 256, 0, stream>>>(idx_ji, pos, tri);

  k_sbfp<<<T_N / 8, 256, 0, stream>>>(sbf, W_sbf1, W_sbf2, sbfp_u);

  phaseA<<<E_N / 128, 1024, 0, stream>>>(x_old, rbf0, wreg, b_kj, b_down, xkj_b);

  k_aggB<<<E_N / 8, 256, 0, stream>>>(counts, tri, idx_kj, sbfp_u,
                                      (const unsigned int*)xkj_b, (unsigned int*)agg_b);

  k_xupg<<<E_N / 4, 256, 0, stream>>>(counts, tri, x1, e1buf);

  phaseC1<<<E_N / 128, 1024, 0, stream>>>(x_old, e1buf, agg_b, wreg,
                                          b_up, b_ji, b_get_up, b_connect, rbB, b_lin, raB,
                                          rbf0, W_rbf, fuse ? e2out : nullptr);
  if (!fuse)
    k_e2<<<E_N * 32 / 256, 256, 0, stream>>>(e1buf, rbf0, W_rbf, e2out);
}

// Round 7
// 1348.362 us; speedup vs baseline: 1.1941x; 1.1941x over previous
//
#include <hip/hip_runtime.h>

#define E_N 262144
#define T_N 1048576

typedef short  bf16x8  __attribute__((ext_vector_type(8)));
typedef short  bf16x4v __attribute__((ext_vector_type(4)));
typedef float  f32x4   __attribute__((ext_vector_type(4)));

// wreg offsets (ushort units)
#define OFF_KJ    0
#define OFF_DOWN  16384
#define OFF_UP    24576
#define OFF_JI    32768
#define OFF_GU    49152
#define OFF_CN    65536
#define OFF_RB0   81920
#define OFF_RB1   98304
#define OFF_LIN   114688
#define OFF_RA00  131072
#define OFF_RA01  147456
#define OFF_RA10  163840
#define OFF_RA11  180224
#define OFF_END   196608   // W12 (f32[6][128]) follows
#define WREG_BYTES 524288u

// byte offsets inside the e2 slot (fallback layout)
#define OFFB_AGG   0u
#define OFFB_XKJ   33554432u
#define OFFB_WREG  67108864u
#define OFFB_CNT   67633152u
#define OFFB_POS   68683776u
#define OFFB_TRI   69732352u
#define OFFB_BS    73926656u
#define OFFB_BP    73927680u

__device__ __forceinline__ float silu_f(float x) { return x / (1.0f + __expf(-x)); }

__device__ __forceinline__ unsigned short f2bf(float f) {
  union { float f; unsigned int u; } v; v.f = f;
  unsigned int u = v.u;
  return (unsigned short)((u + 0x7fffu + ((u >> 16) & 1u)) >> 16);   // RNE
}
__device__ __forceinline__ float bf2f(unsigned short h) {
  union { unsigned int u; float f; } v; v.u = ((unsigned int)h) << 16;
  return v.f;
}

__device__ __forceinline__ unsigned cvtpk(float lo, float hi) {
  unsigned r;
  asm("v_cvt_pk_bf16_f32 %0, %1, %2" : "=v"(r) : "v"(lo), "v"(hi));
  return r;
}

// ---- stage [NR][NC] f32 global tile -> swizzled bf16 LDS tile ----
template<int NC, int NR, int NTH>
__device__ __forceinline__ void stage_tile(const float* __restrict__ g, char* __restrict__ lds) {
  constexpr int RB = NC * 2;
  constexpr int C4 = NC / 4;
  for (int i = threadIdx.x; i < NR * C4; i += NTH) {
    int r = i / C4, c4 = i % C4;
    float4 v = *(const float4*)(g + (size_t)r * NC + c4 * 4);
    bf16x4v h;
    h[0] = (short)f2bf(v.x); h[1] = (short)f2bf(v.y);
    h[2] = (short)f2bf(v.z); h[3] = (short)f2bf(v.w);
    *(bf16x4v*)(lds + r * RB + ((c4 * 8) ^ ((r & 7) << 4))) = h;
  }
}

// ---- stage [64][64] bf16 global tile -> swizzled LDS (straight copy), 512 thr ----
__device__ __forceinline__ void stage_tile_bf16_64(const unsigned short* __restrict__ g,
                                                   char* __restrict__ lds) {
  int i = threadIdx.x;            // 512 threads, 512 16B-chunks (64 rows x 8)
  int r = i >> 3, c = i & 7;
  int4 v = *(const int4*)((const char*)g + r * 128 + c * 16);
  *(int4*)(lds + r * 128 + ((c * 16) ^ ((r & 7) << 4))) = v;
}

// ---- MFMA GEMM: swizzled LDS A-tile  @  WT[N][K] bf16 (global) ----
template<int MREP, int NREP, int KSTEPS, int RB>
__device__ __forceinline__ void mfma_gemm(const char* __restrict__ lds, int row0, int col0,
                                          const unsigned short* __restrict__ WT, int lane,
                                          f32x4 (&acc)[MREP][NREP]) {
  const int kg = lane >> 4, r15 = lane & 15;
#pragma unroll
  for (int m = 0; m < MREP; ++m)
#pragma unroll
    for (int n = 0; n < NREP; ++n) acc[m][n] = (f32x4){0.f, 0.f, 0.f, 0.f};
#pragma unroll
  for (int kk = 0; kk < KSTEPS; ++kk) {
    bf16x8 a[MREP], bfr[NREP];
#pragma unroll
    for (int m = 0; m < MREP; ++m) {
      int row = row0 + m * 16 + r15;
      a[m] = *(const bf16x8*)(lds + row * RB + ((kk * 64 + kg * 16) ^ ((row & 7) << 4)));
    }
#pragma unroll
    for (int n = 0; n < NREP; ++n) {
      int nc = col0 + n * 16 + r15;
      bfr[n] = *(const bf16x8*)((const short*)WT + nc * (KSTEPS * 32) + kk * 32 + kg * 8);
    }
#pragma unroll
    for (int m = 0; m < MREP; ++m)
#pragma unroll
      for (int n = 0; n < NREP; ++n)
        acc[m][n] = __builtin_amdgcn_mfma_f32_16x16x32_bf16(a[m], bfr[n], acc[m][n], 0, 0, 0);
  }
}

// ---- write 2x2 fragment set (f32) as bf16 into swizzled LDS tile (cvt_pk packed) ----
template<int RB>
__device__ __forceinline__ void write_cd(char* __restrict__ lds, int wrow, int wcol, int lane,
                                         const f32x4 (&v)[2][2]) {
  const int kg = lane >> 4, r15 = lane & 15;
#pragma unroll
  for (int m = 0; m < 2; ++m)
#pragma unroll
    for (int n = 0; n < 2; ++n) {
      int col2 = (wcol + n * 16 + r15) * 2;
      int row0 = wrow + m * 16 + kg * 4;
      unsigned u0 = cvtpk(v[m][n][0], v[m][n][1]);
      unsigned u1 = cvtpk(v[m][n][2], v[m][n][3]);
      *(unsigned short*)(lds + (row0 + 0) * RB + (col2 ^ (((row0 + 0) & 7) << 4))) = (unsigned short)u0;
      *(unsigned short*)(lds + (row0 + 1) * RB + (col2 ^ (((row0 + 1) & 7) << 4))) = (unsigned short)(u0 >> 16);
      *(unsigned short*)(lds + (row0 + 2) * RB + (col2 ^ (((row0 + 2) & 7) << 4))) = (unsigned short)u1;
      *(unsigned short*)(lds + (row0 + 3) * RB + (col2 ^ (((row0 + 3) & 7) << 4))) = (unsigned short)(u1 >> 16);
    }
}

// ---- prep: transpose weights to bf16 WT[N][K]; W12 = W_rbf1@W_rbf2 ----
__global__ void __launch_bounds__(256) k_prep(
    const float* __restrict__ W_kj, const float* __restrict__ W_down,
    const float* __restrict__ W_up, const float* __restrict__ W_ji,
    const float* __restrict__ W_get_up, const float* __restrict__ W_connect,
    const float* __restrict__ rbW, const float* __restrict__ W_lin,
    const float* __restrict__ raW,
    const float* __restrict__ W_rbf1, const float* __restrict__ W_rbf2,
    unsigned short* __restrict__ wreg) {
  int b = blockIdx.x;
  if (b == 13) {
    float* W12 = (float*)(wreg + OFF_END);
    for (int i = threadIdx.x; i < 768; i += 256) {
      int r = i >> 7, n = i & 127;
      float s = 0.f;
#pragma unroll
      for (int q = 0; q < 8; ++q) s += W_rbf1[r * 8 + q] * W_rbf2[q * 128 + n];
      W12[i] = s;
    }
    return;
  }
  const float* src; int K = 128, N = 128; int off;
  switch (b) {
    case 0:  src = W_kj;          off = OFF_KJ;  break;
    case 1:  src = W_down;        off = OFF_DOWN; N = 64;  break;
    case 2:  src = W_up;          off = OFF_UP;   K = 64;  break;
    case 3:  src = W_ji;          off = OFF_JI;  break;
    case 4:  src = W_get_up;      off = OFF_GU;  break;
    case 5:  src = W_connect;     off = OFF_CN;  break;
    case 6:  src = rbW;           off = OFF_RB0; break;
    case 7:  src = rbW + 16384;   off = OFF_RB1; break;
    case 8:  src = W_lin;         off = OFF_LIN; break;
    case 9:  src = raW;           off = OFF_RA00; break;
    case 10: src = raW + 16384;   off = OFF_RA01; break;
    case 11: src = raW + 32768;   off = OFF_RA10; break;
    default: src = raW + 49152;   off = OFF_RA11; break;
  }
  unsigned short* dst = wreg + off;
  for (int i = threadIdx.x; i < K * N; i += 256) {
    int k = i / N, n = i % N;
    dst[n * K + k] = f2bf(src[i]);
  }
}

// ================= CSR build (by idx_ji) =================
__global__ void __launch_bounds__(256) k_hist(const int* __restrict__ idx_ji,
                                              int* __restrict__ counts) {
  int t = blockIdx.x * 256 + threadIdx.x;
  atomicAdd(&counts[idx_ji[t]], 1);
}

__global__ void __launch_bounds__(1024) k_scan1(const int* __restrict__ counts,
                                                int* __restrict__ locpre,
                                                int* __restrict__ bsum) {
  __shared__ int s[1024];
  int i = blockIdx.x * 1024 + threadIdx.x;
  int v = counts[i];
  s[threadIdx.x] = v; __syncthreads();
  for (int o = 1; o < 1024; o <<= 1) {
    int t = (threadIdx.x >= o) ? s[threadIdx.x - o] : 0;
    __syncthreads();
    s[threadIdx.x] += t;
    __syncthreads();
  }
  locpre[i] = s[threadIdx.x] - v;
  if (threadIdx.x == 1023) bsum[blockIdx.x] = s[1023];
}

__global__ void __launch_bounds__(256) k_scan2(const int* __restrict__ bsum,
                                               int* __restrict__ bpre, int* __restrict__ offs) {
  __shared__ int s[256];
  int v = bsum[threadIdx.x];
  s[threadIdx.x] = v; __syncthreads();
  for (int o = 1; o < 256; o <<= 1) {
    int t = (threadIdx.x >= o) ? s[threadIdx.x - o] : 0;
    __syncthreads();
    s[threadIdx.x] += t;
    __syncthreads();
  }
  bpre[threadIdx.x] = s[threadIdx.x] - v;
  if (threadIdx.x == 0) offs[E_N] = T_N;
}

__global__ void __launch_bounds__(1024) k_scan3(const int* __restrict__ locpre,
                                                const int* __restrict__ bpre,
                                                int* __restrict__ offs,
                                                int* __restrict__ pos) {
  int i = blockIdx.x * 1024 + threadIdx.x;
  int v = locpre[i] + bpre[blockIdx.x];
  offs[i] = v;
  pos[i] = v;
}

__global__ void __launch_bounds__(256) k_fill(const int* __restrict__ idx_ji,
                                              int* __restrict__ pos, int* __restrict__ tri) {
  int t = blockIdx.x * 256 + threadIdx.x;
  int e = idx_ji[t];
  int slot = atomicAdd(&pos[e], 1);
  tri[slot] = t;
}

// ================= dense sbf_p: [T][64] bf16 =================
__global__ void __launch_bounds__(256) k_sbfp(const float* __restrict__ sbf,
                                              const float* __restrict__ W_sbf1,
                                              const float* __restrict__ W_sbf2,
                                              unsigned int* __restrict__ sbfp) {
  __shared__ float s_s[8][42];
  __shared__ float s_t8[8][8];
  int t0 = blockIdx.x * 8;
  for (int i = threadIdx.x; i < 8 * 42; i += 256)
    s_s[i / 42][i % 42] = sbf[(size_t)t0 * 42 + i];
  __syncthreads();
  if (threadIdx.x < 64) {
    int w8 = threadIdx.x >> 3, bb = threadIdx.x & 7;
    float s = 0.f;
#pragma unroll
    for (int r = 0; r < 42; ++r) s += s_s[w8][r] * W_sbf1[r * 8 + bb];
    s_t8[w8][bb] = s;
  }
  __syncthreads();
  int w8 = threadIdx.x >> 5, jj = threadIdx.x & 31;
  float sp0 = 0.f, sp1 = 0.f;
#pragma unroll
  for (int bb = 0; bb < 8; ++bb) {
    float tv = s_t8[w8][bb];
    sp0 += tv * W_sbf2[bb * 64 + jj * 2];
    sp1 += tv * W_sbf2[bb * 64 + jj * 2 + 1];
  }
  unsigned int u = (unsigned int)f2bf(sp0) | ((unsigned int)f2bf(sp1) << 16);
  sbfp[(size_t)(t0 + w8) * 32 + jj] = u;
}

// ================= gather: agg[e][j] = sum_t sbfp[t][j]*xkj[idx_kj[t]][j] =================
__global__ void __launch_bounds__(256) k_aggB(const int* __restrict__ offs,
                                              const int* __restrict__ tri,
                                              const int* __restrict__ idx_kj,
                                              const unsigned int* __restrict__ sbfp,
                                              const unsigned int* __restrict__ xkj,
                                              unsigned int* __restrict__ agg) {
  int sub = threadIdx.x >> 5, jj = threadIdx.x & 31;
  int e = blockIdx.x * 8 + sub;
  int o0 = offs[e], o1 = offs[e + 1];
  float a0 = 0.f, a1 = 0.f;
  for (int i = o0; i < o1; ++i) {
    int t = tri[i];
    int kj = idx_kj[t];
    unsigned int sv = sbfp[(size_t)t * 32 + jj];
    unsigned int xv = xkj[(size_t)kj * 32 + jj];
    a0 += bf2f((unsigned short)(sv & 0xffff)) * bf2f((unsigned short)(xv & 0xffff));
    a1 += bf2f((unsigned short)(sv >> 16)) * bf2f((unsigned short)(xv >> 16));
  }
  agg[(size_t)e * 32 + jj] = (unsigned int)f2bf(a0) | ((unsigned int)f2bf(a1) << 16);
}

// ================= gather: x_up_raw[e][h] = sum_t x1[t][h] =================
__global__ void __launch_bounds__(256) k_xupg(const int* __restrict__ offs,
                                              const int* __restrict__ tri,
                                              const float* __restrict__ x1,
                                              float* __restrict__ out) {
  int sub = threadIdx.x >> 6, h2 = threadIdx.x & 63;
  int e = blockIdx.x * 4 + sub;
  int o0 = offs[e], o1 = offs[e + 1];
  float a0 = 0.f, a1 = 0.f;
  for (int i = o0; i < o1; ++i) {
    int t = tri[i];
    float2 v = *(const float2*)(x1 + (size_t)t * 128 + h2 * 2);
    a0 += v.x; a1 += v.y;
  }
  *(float2*)(out + (size_t)e * 128 + h2 * 2) = make_float2(a0, a1);
}

// ================= Phase A (R4 structure, cvt_pk pack, 2 barriers) =================
__global__ void __launch_bounds__(512, 4) phaseA(
    const float* __restrict__ x_old, const float* __restrict__ rbf0,
    const unsigned short* __restrict__ wreg,
    const float* __restrict__ b_kj, const float* __restrict__ b_down,
    unsigned short* __restrict__ xkjdown) {
  __shared__ char lds[32768];
  char* B0 = lds;
  char* B1 = lds + 16384;
  const int tid = threadIdx.x, lane = tid & 63, wave = tid >> 6;
  const int kg = lane >> 4, r15 = lane & 15;
  const int wrow = (wave >> 2) * 32, wcol = (wave & 3) * 32;
  const size_t e_base = (size_t)blockIdx.x * 64;
  const float* W12 = (const float*)(wreg + OFF_END);

  stage_tile<128, 64, 512>(x_old + e_base * 128, B0);
  __syncthreads();

  f32x4 acc[2][2], val[2][2];
  mfma_gemm<2, 2, 4, 256>(B0, wrow, wcol, wreg + OFF_KJ, lane, acc);
#pragma unroll
  for (int n = 0; n < 2; ++n) {
    int col = wcol + n * 16 + r15;
    float bk = b_kj[col];
    float wc[6];
#pragma unroll
    for (int q = 0; q < 6; ++q) wc[q] = W12[q * 128 + col];
#pragma unroll
    for (int m = 0; m < 2; ++m)
#pragma unroll
      for (int r = 0; r < 4; ++r) {
        int row = wrow + m * 16 + kg * 4 + r;
        const float* rp = rbf0 + (e_base + row) * 6;
        float rv = rp[0]*wc[0] + rp[1]*wc[1] + rp[2]*wc[2] + rp[3]*wc[3] + rp[4]*wc[4] + rp[5]*wc[5];
        val[m][n][r] = silu_f(acc[m][n][r] + bk) * rv;
      }
  }
  write_cd<256>(B1, wrow, wcol, lane, val);   // B1 fresh: no pre-barrier needed
  __syncthreads();

  const int wrow2 = (wave >> 1) * 16, wcol2 = (wave & 1) * 32;
  f32x4 a2[1][2];
  mfma_gemm<1, 2, 4, 256>(B1, wrow2, wcol2, wreg + OFF_DOWN, lane, a2);
#pragma unroll
  for (int n = 0; n < 2; ++n) {
    int col = wcol2 + n * 16 + r15;
    float bd = b_down[col];
#pragma unroll
    for (int r = 0; r < 4; ++r) {
      int row = wrow2 + kg * 4 + r;
      xkjdown[(e_base + row) * 64 + col] = f2bf(silu_f(a2[0][n][r] + bd));
    }
  }
}

// ================= Phase C1: triple-buffer rotation, 1 barrier/stage =================
__global__ void __launch_bounds__(512, 4) phaseC1(
    const float* __restrict__ x_old, float* __restrict__ e1buf,
    const unsigned short* __restrict__ agg, const unsigned short* __restrict__ wreg,
    const float* __restrict__ b_up, const float* __restrict__ b_ji,
    const float* __restrict__ b_get_up, const float* __restrict__ b_connect,
    const float* __restrict__ rbB, const float* __restrict__ b_lin,
    const float* __restrict__ raB,
    const float* __restrict__ rbf0, const float* __restrict__ W_rbf,
    float* __restrict__ e2o) {
  __shared__ char lds[73728];   // X0,X1,X2 (3x16K) + XOLD (16K) + AGGB (8K) = 72 KB
  char* X0   = lds;
  char* X1   = lds + 16384;
  char* X2   = lds + 32768;
  char* XOLD = lds + 49152;
  char* AGGB = lds + 65536;
  const int tid = threadIdx.x, lane = tid & 63, wave = tid >> 6;
  const int kg = lane >> 4, r15 = lane & 15;
  const int wrow = (wave >> 2) * 32, wcol = (wave & 3) * 32;
  const size_t e_base = (size_t)blockIdx.x * 64;

  stage_tile<128, 64, 512>(x_old + e_base * 128, XOLD);
  stage_tile<128, 64, 512>(e1buf + e_base * 128, X1);   // x_up_raw
  stage_tile_bf16_64(agg + e_base * 64, AGGB);
  __syncthreads();

  f32x4 acc[2][2], keep[2][2], h[2][2];

  // S1: h = silu(agg@W_up + b_up)
  mfma_gemm<2, 2, 2, 128>(AGGB, wrow, wcol, wreg + OFF_UP, lane, acc);
#pragma unroll
  for (int n = 0; n < 2; ++n) {
    float bu = b_up[wcol + n * 16 + r15];
#pragma unroll
    for (int m = 0; m < 2; ++m)
#pragma unroll
      for (int r = 0; r < 4; ++r) h[m][n][r] = silu_f(acc[m][n][r] + bu);
  }
  // S2: keep(e1a) = silu(XOLD@W_ji + b_ji) + h -> X0 ; barrier
  mfma_gemm<2, 2, 4, 256>(XOLD, wrow, wcol, wreg + OFF_JI, lane, acc);
#pragma unroll
  for (int n = 0; n < 2; ++n) {
    float bj = b_ji[wcol + n * 16 + r15];
#pragma unroll
    for (int m = 0; m < 2; ++m)
#pragma unroll
      for (int r = 0; r < 4; ++r) keep[m][n][r] = silu_f(acc[m][n][r] + bj) + h[m][n][r];
  }
  write_cd<256>(X0, wrow, wcol, lane, keep);
  __syncthreads();

  // S3: h = silu(X1(x_up_raw)@W_get_up + b)
  mfma_gemm<2, 2, 4, 256>(X1, wrow, wcol, wreg + OFF_GU, lane, acc);
#pragma unroll
  for (int n = 0; n < 2; ++n) {
    float bg = b_get_up[wcol + n * 16 + r15];
#pragma unroll
    for (int m = 0; m < 2; ++m)
#pragma unroll
      for (int r = 0; r < 4; ++r) h[m][n][r] = silu_f(acc[m][n][r] + bg);
  }
  // S4: keep(e1b) = silu(X0@W_connect + b) + h -> X2 ; barrier
  mfma_gemm<2, 2, 4, 256>(X0, wrow, wcol, wreg + OFF_CN, lane, acc);
#pragma unroll
  for (int n = 0; n < 2; ++n) {
    float bc = b_connect[wcol + n * 16 + r15];
#pragma unroll
    for (int m = 0; m < 2; ++m)
#pragma unroll
      for (int r = 0; r < 4; ++r) keep[m][n][r] = silu_f(acc[m][n][r] + bc) + h[m][n][r];
  }
  write_cd<256>(X2, wrow, wcol, lane, keep);
  __syncthreads();

  // S5: tmp = silu(X2@rb0 + b) -> X0 ; barrier   [X0 last read S4, barrier'd]
  mfma_gemm<2, 2, 4, 256>(X2, wrow, wcol, wreg + OFF_RB0, lane, acc);
#pragma unroll
  for (int n = 0; n < 2; ++n) {
    float bv = rbB[wcol + n * 16 + r15];
#pragma unroll
    for (int m = 0; m < 2; ++m)
#pragma unroll
      for (int r = 0; r < 4; ++r) h[m][n][r] = silu_f(acc[m][n][r] + bv);
  }
  write_cd<256>(X0, wrow, wcol, lane, h);
  __syncthreads();

  // S6: keep(e1c) += silu(X0@rb1 + b) -> X1 ; barrier   [X1 last read S3]
  mfma_gemm<2, 2, 4, 256>(X0, wrow, wcol, wreg + OFF_RB1, lane, acc);
#pragma unroll
  for (int n = 0; n < 2; ++n) {
    float bv = rbB[128 + wcol + n * 16 + r15];
#pragma unroll
    for (int m = 0; m < 2; ++m)
#pragma unroll
      for (int r = 0; r < 4; ++r) keep[m][n][r] += silu_f(acc[m][n][r] + bv);
  }
  write_cd<256>(X1, wrow, wcol, lane, keep);
  __syncthreads();

  // S7: keep(e1d) = silu(X1@W_lin + b) + x_old(LDS) -> X2 ; barrier  [X2 last read S5]
  mfma_gemm<2, 2, 4, 256>(X1, wrow, wcol, wreg + OFF_LIN, lane, acc);
#pragma unroll
  for (int n = 0; n < 2; ++n) {
    int col = wcol + n * 16 + r15;
    float bl = b_lin[col];
#pragma unroll
    for (int m = 0; m < 2; ++m)
#pragma unroll
      for (int r = 0; r < 4; ++r) {
        int row = wrow + m * 16 + kg * 4 + r;
        float xo = bf2f(*(const unsigned short*)(XOLD + row * 256 + ((col * 2) ^ ((row & 7) << 4))));
        keep[m][n][r] = silu_f(acc[m][n][r] + bl) + xo;
      }
  }
  write_cd<256>(X2, wrow, wcol, lane, keep);
  __syncthreads();

  // S8: tmp = silu(X2@ra00 + b) -> X0 ; barrier  [X0 last read S6]
  mfma_gemm<2, 2, 4, 256>(X2, wrow, wcol, wreg + OFF_RA00, lane, acc);
#pragma unroll
  for (int n = 0; n < 2; ++n) {
    float bv = raB[wcol + n * 16 + r15];
#pragma unroll
    for (int m = 0; m < 2; ++m)
#pragma unroll
      for (int r = 0; r < 4; ++r) h[m][n][r] = silu_f(acc[m][n][r] + bv);
  }
  write_cd<256>(X0, wrow, wcol, lane, h);
  __syncthreads();

  // S9: keep(e1e) += silu(X0@ra01 + b) -> X1 ; barrier  [X1 last read S7]
  mfma_gemm<2, 2, 4, 256>(X0, wrow, wcol, wreg + OFF_RA01, lane, acc);
#pragma unroll
  for (int n = 0; n < 2; ++n) {
    float bv = raB[128 + wcol + n * 16 + r15];
#pragma unroll
    for (int m = 0; m < 2; ++m)
#pragma unroll
      for (int r = 0; r < 4; ++r) keep[m][n][r] += silu_f(acc[m][n][r] + bv);
  }
  write_cd<256>(X1, wrow, wcol, lane, keep);
  __syncthreads();

  // S10: tmp = silu(X1@ra10 + b) -> X2 ; barrier  [X2 last read S8]
  mfma_gemm<2, 2, 4, 256>(X1, wrow, wcol, wreg + OFF_RA10, lane, acc);
#pragma unroll
  for (int n = 0; n < 2; ++n) {
    float bv = raB[256 + wcol + n * 16 + r15];
#pragma unroll
    for (int m = 0; m < 2; ++m)
#pragma unroll
      for (int r = 0; r < 4; ++r) h[m][n][r] = silu_f(acc[m][n][r] + bv);
  }
  write_cd<256>(X2, wrow, wcol, lane, h);
  __syncthreads();

  // S11: e1 = keep + silu(X2@ra11 + b) -> global ; fused e2
  mfma_gemm<2, 2, 4, 256>(X2, wrow, wcol, wreg + OFF_RA11, lane, acc);
#pragma unroll
  for (int n = 0; n < 2; ++n) {
    int col = wcol + n * 16 + r15;
    float bv = raB[384 + col];
    float wc[6];
#pragma unroll
    for (int q = 0; q < 6; ++q) wc[q] = W_rbf[q * 128 + col];
#pragma unroll
    for (int m = 0; m < 2; ++m)
#pragma unroll
      for (int r = 0; r < 4; ++r) {
        int row = wrow + m * 16 + kg * 4 + r;
        size_t e = e_base + row;
        float val = keep[m][n][r] + silu_f(acc[m][n][r] + bv);
        e1buf[e * 128 + col] = val;
        if (e2o) {
          const float* rp = rbf0 + e * 6;
          float rv = rp[0]*wc[0] + rp[1]*wc[1] + rp[2]*wc[2] + rp[3]*wc[3] + rp[4]*wc[4] + rp[5]*wc[5];
          e2o[e * 128 + col] = val * rv;
        }
      }
  }
}

// ---- fallback C2 epilogue: e2 = (rbf0 @ W_rbf) * e1 ----
__global__ void __launch_bounds__(256) k_e2(const float* __restrict__ e1,
                                            const float* __restrict__ rbf0,
                                            const float* __restrict__ W_rbf,
                                            float* __restrict__ e2) {
  size_t gid = (size_t)blockIdx.x * 256 + threadIdx.x;
  int e = (int)(gid >> 5);
  int c = (int)(gid & 31) << 2;
  float r6[6];
#pragma unroll
  for (int r = 0; r < 6; ++r) r6[r] = rbf0[(size_t)e * 6 + r];
  float4 v = *(const float4*)(e1 + (size_t)e * 128 + c);
  float4 o;
  float rv;
  rv = 0.f;
#pragma unroll
  for (int r = 0; r < 6; ++r) rv += r6[r] * W_rbf[r * 128 + c + 0];
  o.x = v.x * rv;
  rv = 0.f;
#pragma unroll
  for (int r = 0; r < 6; ++r) rv += r6[r] * W_rbf[r * 128 + c + 1];
  o.y = v.y * rv;
  rv = 0.f;
#pragma unroll
  for (int r = 0; r < 6; ++r) rv += r6[r] * W_rbf[r * 128 + c + 2];
  o.z = v.z * rv;
  rv = 0.f;
#pragma unroll
  for (int r = 0; r < 6; ++r) rv += r6[r] * W_rbf[r * 128 + c + 3];
  o.w = v.w * rv;
  *(float4*)(e2 + (size_t)e * 128 + c) = o;
}

extern "C" void kernel_launch(void* const* d_in, const int* in_sizes, int n_in,
                              void* d_out, int out_size, void* d_ws, size_t ws_size,
                              hipStream_t stream) {
  const float* x1        = (const float*)d_in[0];
  const float* x_old     = (const float*)d_in[1];
  const float* rbf0      = (const float*)d_in[2];
  const float* sbf       = (const float*)d_in[3];
  const int*   idx_kj    = (const int*)d_in[4];
  const int*   idx_ji    = (const int*)d_in[5];
  const float* W_rbf1    = (const float*)d_in[6];
  const float* W_rbf2    = (const float*)d_in[7];
  const float* W_sbf1    = (const float*)d_in[8];
  const float* W_sbf2    = (const float*)d_in[9];
  const float* W_rbf     = (const float*)d_in[10];
  const float* W_kj      = (const float*)d_in[11];
  const float* b_kj      = (const float*)d_in[12];
  const float* W_ji      = (const float*)d_in[13];
  const float* b_ji      = (const float*)d_in[14];
  const float* W_connect = (const float*)d_in[15];
  const float* b_connect = (const float*)d_in[16];
  const float* W_get_up  = (const float*)d_in[17];
  const float* b_get_up  = (const float*)d_in[18];
  const float* W_down    = (const float*)d_in[19];
  const float* b_down    = (const float*)d_in[20];
  const float* W_up      = (const float*)d_in[21];
  const float* b_up      = (const float*)d_in[22];
  const float* rbW       = (const float*)d_in[23];
  const float* rbB       = (const float*)d_in[24];
  const float* W_lin     = (const float*)d_in[25];
  const float* b_lin     = (const float*)d_in[26];
  const float* raW       = (const float*)d_in[27];
  const float* raB       = (const float*)d_in[28];

  float* e1buf = (float*)d_out;                      // sbf_p -> x_up_raw -> e1
  char*  base2 = (char*)d_out + (size_t)E_N * 128 * 4;
  float* e2out = (float*)base2;

  unsigned short* xkj_b = (unsigned short*)(base2 + OFFB_XKJ);
  int* counts = (int*)(base2 + OFFB_CNT);
  int* pos    = (int*)(base2 + OFFB_POS);
  int* tri    = (int*)(base2 + OFFB_TRI);
  int* bsum   = (int*)(base2 + OFFB_BS);
  int* bpre   = (int*)(base2 + OFFB_BP);

  const size_t need_ws = (size_t)WREG_BYTES + (size_t)E_N * 64 * 2;
  const bool fuse = ws_size >= need_ws;
  unsigned short* wreg  = fuse ? (unsigned short*)d_ws
                               : (unsigned short*)(base2 + OFFB_WREG);
  unsigned short* agg_b = fuse ? (unsigned short*)((char*)d_ws + WREG_BYTES)
                               : (unsigned short*)(base2 + OFFB_AGG);

  unsigned int* sbfp_u = (unsigned int*)e1buf;   // bf16x2 [T][32] transient in e1 slot

  k_prep<<<14, 256, 0, stream>>>(W_kj, W_down, W_up, W_ji, W_get_up, W_connect,
                                 rbW, W_lin, raW, W_rbf1, W_rbf2, wreg);

  hipMemsetAsync(counts, 0, (E_N + 1) * sizeof(int), stream);
  k_hist<<<T_N / 256, 256, 0, stream>>>(idx_ji, counts);
  k_scan1<<<256, 1024, 0, stream>>>(counts, pos, bsum);
  k_scan2<<<1, 256, 0, stream>>>(bsum, bpre, counts);
  k_scan3<<<256, 1024, 0, stream>>>(pos, bpre, counts, pos);
  k_fill<<<T_N / 256, 256, 0, stream>>>(idx_ji, pos, tri);

  k_sbfp<<<T_N / 8, 256, 0, stream>>>(sbf, W_sbf1, W_sbf2, sbfp_u);

  phaseA<<<E_N / 64, 512, 0, stream>>>(x_old, rbf0, wreg, b_kj, b_down, xkj_b);

  k_aggB<<<E_N / 8, 256, 0, stream>>>(counts, tri, idx_kj, sbfp_u,
                                      (const unsigned int*)xkj_b, (unsigned int*)agg_b);

  k_xupg<<<E_N / 4, 256, 0, stream>>>(counts, tri, x1, e1buf);

  phaseC1<<<E_N / 64, 512, 0, stream>>>(x_old, e1buf, agg_b, wreg,
                                        b_up, b_ji, b_get_up, b_connect, rbB, b_lin, raB,
                                        rbf0, W_rbf, fuse ? e2out : nullptr);
  if (!fuse)
    k_e2<<<E_N * 32 / 256, 256, 0, stream>>>(e1buf, rbf0, W_rbf, e2out);
}